// Round 4
// baseline (280.902 us; speedup 1.0000x reference)
//
#include <hip/hip_runtime.h>

typedef __bf16 bf16;
typedef __bf16 bf16x8 __attribute__((ext_vector_type(8)));
typedef __bf16 bf16x4 __attribute__((ext_vector_type(4)));
typedef float f32x4 __attribute__((ext_vector_type(4)));
typedef float fx2 __attribute__((ext_vector_type(2)));
typedef unsigned int u32x2 __attribute__((ext_vector_type(2)));

#define DEV static __device__ __forceinline__

constexpr int BB = 2, SS = 2048, DM = 1024, NH = 16, HD = 64;
constexpr int MTOT = BB * SS;  // 4096
constexpr float LOG2E = 1.4426950408889634f;

// ---- workspace layout (bytes) ----
constexpr size_t OFF_XB   = 0;                                  // bf16 [4096][1024]
constexpr size_t OFF_WQKV = OFF_XB   + (size_t)MTOT * DM * 2;   // bf16 [3072][1024]
constexpr size_t OFF_WO   = OFF_WQKV + (size_t)3 * DM * DM * 2; // bf16 [1024][1024]
constexpr size_t OFF_TAB  = OFF_WO   + (size_t)DM * DM * 2;     // fx2  [2048][32]
constexpr size_t OFF_Q    = OFF_TAB  + (size_t)SS * (HD/2) * 8; // bf16 (B,H,S,d)
constexpr size_t OFF_K    = OFF_Q    + (size_t)MTOT * DM * 2;
constexpr size_t OFF_VT   = OFF_K    + (size_t)MTOT * DM * 2;   // bf16 (B,H,d,S)
constexpr size_t OFF_AO   = OFF_VT   + (size_t)MTOT * DM * 2;   // bf16 [4096][1024]

typedef const __attribute__((address_space(1))) void gas_void;
typedef __attribute__((address_space(3))) void las_void;

DEV void gload16(const bf16* g, bf16* l) {
  __builtin_amdgcn_global_load_lds((gas_void*)g, (las_void*)l, 16, 0, 0);
}

DEV f32x4 mfma16(bf16x8 a, bf16x8 b, f32x4 c) {
  return __builtin_amdgcn_mfma_f32_16x16x32_bf16(a, b, c, 0, 0, 0);
}

DEV unsigned pack2(float a, float b) {
  union { bf16 h[2]; unsigned u; } cv;
  cv.h[0] = (bf16)a; cv.h[1] = (bf16)b;
  return cv.u;
}

DEV u32x2 tr_read(unsigned addr) {
  u32x2 r;
  asm volatile("ds_read_b64_tr_b16 %0, %1" : "=v"(r) : "v"(addr));
  return r;
}

DEV bf16x8 combine4(u32x2 r0, u32x2 r1) {
  union { unsigned u[4]; bf16x8 v; } cv;
  cv.u[0] = r0[0]; cv.u[1] = r0[1]; cv.u[2] = r1[0]; cv.u[3] = r1[1];
  return cv.v;
}

// ---------------- prep: fp32 -> bf16 casts + RoPE table ----------------
__global__ void prep_kernel(const float* __restrict__ x, const float* __restrict__ wq,
    const float* __restrict__ wk, const float* __restrict__ wv, const float* __restrict__ wo,
    const int* __restrict__ pos, bf16* __restrict__ xb, bf16* __restrict__ wqkv,
    bf16* __restrict__ wob, fx2* __restrict__ tab) {
  const int NX4 = MTOT * DM / 4;     // 1048576
  const int NW4 = DM * DM / 4;       // 262144 = 2^18
  const int TOTC = NX4 + 4 * NW4;    // 2097152
  const int NTAB = SS * (HD / 2);    // 65536
  const int total = TOTC + NTAB;
  for (int i = blockIdx.x * blockDim.x + threadIdx.x; i < total; i += gridDim.x * blockDim.x) {
    if (i < TOTC) {
      const float* src; bf16* dst; int off;
      if (i < NX4) { src = x; dst = xb; off = i; }
      else {
        int i2 = i - NX4; int which = i2 >> 18; off = i2 & (NW4 - 1);
        src = which == 0 ? wq : which == 1 ? wk : which == 2 ? wv : wo;
        dst = which == 0 ? wqkv : which == 1 ? wqkv + DM * DM : which == 2 ? wqkv + 2 * DM * DM : wob;
      }
      float4 v = ((const float4*)src)[off];
      bf16x4 o4 = { (bf16)v.x, (bf16)v.y, (bf16)v.z, (bf16)v.w };
      ((bf16x4*)dst)[off] = o4;
    } else {
      int e = i - TOTC;
      int s = e >> 5, p = e & 31;
      float invf = __builtin_exp2f(-(float)p * (13.287712379549449f / 32.0f));
      float ang = (float)pos[s] * invf;
      fx2 cs; cs.x = cosf(ang); cs.y = sinf(ang);
      tab[e] = cs;
    }
  }
}

// ---------------- 128x128 bf16 GEMM mainloop (C[m,n] = sum_k A[m,k]*B[n,k]) ----------------
DEV void gemm_bt_128(const bf16* __restrict__ A, const bf16* __restrict__ Bw,
                     int rowA0, int rowB0, f32x4 (&acc)[4][4]) {
  __shared__ __align__(16) bf16 lA[128 * 32];
  __shared__ __align__(16) bf16 lB[128 * 32];
  const int t = threadIdx.x, w = t >> 6, lane = t & 63;
  const int wr = w >> 1, wc = w & 1, g = lane >> 4, c = lane & 15;
#pragma unroll
  for (int mi = 0; mi < 4; mi++)
#pragma unroll
    for (int ni = 0; ni < 4; ni++) acc[mi][ni] = (f32x4){0.f, 0.f, 0.f, 0.f};
  const bf16* ga = A + (size_t)(rowA0 + (t >> 2)) * DM + (t & 3) * 8;
  const bf16* gb = Bw + (size_t)(rowB0 + (t >> 2)) * DM + (t & 3) * 8;
  bf16* la = lA + w * 512;
  bf16* lb = lB + w * 512;
  const int arow = wr * 64 + c, brow = wc * 64 + c;
  for (int k0 = 0; k0 < DM; k0 += 32) {
    gload16(ga + k0,            la);
    gload16(ga + k0 + 64 * DM,  la + 2048);
    gload16(gb + k0,            lb);
    gload16(gb + k0 + 64 * DM,  lb + 2048);
    __syncthreads();
    bf16x8 af[4], bf_[4];
#pragma unroll
    for (int mi = 0; mi < 4; mi++) af[mi]  = *(const bf16x8*)(lA + (arow + mi * 16) * 32 + g * 8);
#pragma unroll
    for (int ni = 0; ni < 4; ni++) bf_[ni] = *(const bf16x8*)(lB + (brow + ni * 16) * 32 + g * 8);
#pragma unroll
    for (int mi = 0; mi < 4; mi++)
#pragma unroll
      for (int ni = 0; ni < 4; ni++)
        acc[mi][ni] = mfma16(af[mi], bf_[ni], acc[mi][ni]);
    __syncthreads();
  }
}

// ---------------- QKV projection + RoPE epilogue ----------------
__global__ __launch_bounds__(256, 2) void qkv_kernel(const bf16* __restrict__ xb,
    const bf16* __restrict__ wqkv, const fx2* __restrict__ tab,
    bf16* __restrict__ Qb, bf16* __restrict__ Kb, bf16* __restrict__ VTb) {
  f32x4 acc[4][4];
  const int rowA0 = blockIdx.y * 128, rowB0 = blockIdx.x * 128;
  gemm_bt_128(xb, wqkv, rowA0, rowB0, acc);
  const int t = threadIdx.x, w = t >> 6, lane = t & 63;
  const int wr = w >> 1, wc = w & 1, g = lane >> 4, c = lane & 15;
  const int which = rowB0 >> 10;
#pragma unroll
  for (int mi = 0; mi < 4; mi++)
#pragma unroll
    for (int ni = 0; ni < 4; ni++) {
      const int ncol = rowB0 + wc * 64 + ni * 16 + c;
      const int nn = ncol & (DM - 1), h = nn >> 6, dd = nn & 63;
#pragma unroll
      for (int j = 0; j < 4; j++) {
        const int mrow = rowA0 + wr * 64 + mi * 16 + 4 * g + j;
        const int b = mrow >> 11, s = mrow & (SS - 1);
        float v = acc[mi][ni][j];
        if (which < 2) {
          float partner = __shfl_xor(v, 1);
          fx2 cs = tab[s * 32 + (dd >> 1)];
          v = v * cs.x + ((dd & 1) ? partner : -partner) * cs.y;
          bf16* dst = which == 0 ? Qb : Kb;
          dst[((size_t)((b * NH + h) * SS + s)) * HD + dd] = (bf16)v;
        } else {
          VTb[((size_t)((b * NH + h) * HD + dd)) * SS + s] = (bf16)v;
        }
      }
    }
}

// ---------------- flash attention (causal), 2 waves/block split-k ----------------
// Block (pi, bh): lo chunk rows [16*pi,16*pi+16), hi chunk rows [2032-16*pi, +16).
// 33 virtual k-tiles per pair (TL = pi/4+1 lo tiles + TH = 33-TL hi tiles).
// Wave 0: v in [0,17)  -> ALL lo tiles + first hi tiles; stores lo directly.
// Wave 1: v in [17,33) -> exactly 16 hi tiles; publishes hi partial via LDS.
// Wave 0 merges the two hi partials (online-softmax merge) and stores hi.
__global__ __launch_bounds__(128, 4) void attn_kernel(const bf16* __restrict__ Q,
    const bf16* __restrict__ K, const bf16* __restrict__ VT, bf16* __restrict__ AO) {
  __shared__ __align__(16) unsigned char pmem[3 * 2048];
  __shared__ float Om[16][64];
  __shared__ float Ml2[2][16];
  const int bh = blockIdx.y;
  const int pi = blockIdx.x;                 // 0..63
  const int tid = threadIdx.x;
  const int w = tid >> 6;
  const int lane = tid & 63, g = lane >> 4, c = lane & 15;
  const bf16* Qp = Q + (size_t)bh * SS * HD;
  const bf16* Kp = K + (size_t)bh * SS * HD;
  const bf16* Vp = VT + (size_t)bh * HD * SS;
  const int ql = pi * 16;
  const int qh = 2032 - pi * 16;
  const int TL = pi / 4 + 1;                 // # lo k-tiles
  const unsigned lbase = (unsigned)(size_t)(__attribute__((address_space(3))) unsigned char*)&pmem[0];

  // Q fragments (A row = c), pre-scaled by 1/sqrt(64)=0.125
  bf16x8 qa_lo[2], qa_hi[2];
#pragma unroll
  for (int kc = 0; kc < 2; kc++) {
    bf16x8 xl = *(const bf16x8*)(Qp + (ql + c) * HD + kc * 32 + g * 8);
    bf16x8 xh = *(const bf16x8*)(Qp + (qh + c) * HD + kc * 32 + g * 8);
#pragma unroll
    for (int e = 0; e < 8; e++) {
      xl[e] = (bf16)((float)xl[e] * 0.125f);
      xh[e] = (bf16)((float)xh[e] * 0.125f);
    }
    qa_lo[kc] = xl; qa_hi[kc] = xh;
  }

  float m_lo[4], l_lo[4], m_hi[4], l_hi[4];
  f32x4 o_lo[4], o_hi[4];
#pragma unroll
  for (int j = 0; j < 4; j++) {
    m_lo[j] = -3.0e38f; l_lo[j] = 0.f; m_hi[j] = -3.0e38f; l_hi[j] = 0.f;
  }
#pragma unroll
  for (int df = 0; df < 4; df++) {
    o_lo[df] = (f32x4){0.f, 0.f, 0.f, 0.f};
    o_hi[df] = (f32x4){0.f, 0.f, 0.f, 0.f};
  }

  // online softmax + P relay for one 16-row chunk
  auto sm_relay = [&](f32x4 (&sc)[4], float (&mr)[4], float (&lr)[4], f32x4 (&oo)[4],
                      unsigned ro) {
    float al[4];
#pragma unroll
    for (int j = 0; j < 4; j++) {
      float mx = fmaxf(fmaxf(sc[0][j], sc[1][j]), fmaxf(sc[2][j], sc[3][j]));
      mx = fmaxf(mx, __shfl_xor(mx, 1));
      mx = fmaxf(mx, __shfl_xor(mx, 2));
      mx = fmaxf(mx, __shfl_xor(mx, 4));
      mx = fmaxf(mx, __shfl_xor(mx, 8));
      const float mold = mr[j];
      const float mnew = fmaxf(mold, mx);
      const float alpha = __builtin_exp2f((mold - mnew) * LOG2E);
      float rs = 0.f;
#pragma unroll
      for (int kf = 0; kf < 4; kf++) {
        float p = __builtin_exp2f((sc[kf][j] - mnew) * LOG2E);
        sc[kf][j] = p; rs += p;
      }
      rs += __shfl_xor(rs, 1);
      rs += __shfl_xor(rs, 2);
      rs += __shfl_xor(rs, 4);
      rs += __shfl_xor(rs, 8);
      lr[j] = alpha * lr[j] + rs;
      mr[j] = mnew;
      al[j] = alpha;
    }
#pragma unroll
    for (int df = 0; df < 4; df++)
#pragma unroll
      for (int j = 0; j < 4; j++) oo[df][j] *= al[j];
#pragma unroll
    for (int kf = 0; kf < 4; kf++) {
      u32x2 pk;
      pk[0] = pack2(sc[kf][0], sc[kf][1]);
      pk[1] = pack2(sc[kf][2], sc[kf][3]);
      const unsigned a = ro + (unsigned)((kf * 16 + c) * 32 + 8 * g);
      *(u32x2*)(pmem + a) = pk;
    }
  };

  const int vbeg = w ? 17 : 0;
  const int vend = w ? 33 : 17;
  for (int v = vbeg; v < vend; ++v) {
    const bool is_lo = (!w) && (v < TL);
    const int k0 = (is_lo ? v : (v - TL)) * 64;
    const int qbase = is_lo ? ql : qh;
    const unsigned ro = is_lo ? 0u : (w ? 4096u : 2048u);
    const bf16x8 q0 = is_lo ? qa_lo[0] : qa_hi[0];
    const bf16x8 q1 = is_lo ? qa_lo[1] : qa_hi[1];
    // ---- QK^T for this 64-key tile ----
    f32x4 sc[4];
#pragma unroll
    for (int kf = 0; kf < 4; kf++) {
      const bf16* kr = Kp + (k0 + kf * 16 + c) * HD + g * 8;
      bf16x8 kb0 = *(const bf16x8*)(kr);
      bf16x8 kb1 = *(const bf16x8*)(kr + 32);
      f32x4 z = (f32x4){0.f, 0.f, 0.f, 0.f};
      z = mfma16(q0, kb0, z);
      z = mfma16(q1, kb1, z);
      sc[kf] = z;
    }
    // ---- V prefetch (hides under softmax) ----
    bf16x8 vb[4][2];
#pragma unroll
    for (int df = 0; df < 4; df++) {
      const bf16* vr = Vp + (df * 16 + c) * SS + k0 + g * 8;
      vb[df][0] = *(const bf16x8*)(vr);
      vb[df][1] = *(const bf16x8*)(vr + 32);
    }
    // ---- causal mask (diagonal tiles only) ----
    if (k0 + 63 > qbase) {
#pragma unroll
      for (int kf = 0; kf < 4; kf++) {
        const int kg = k0 + kf * 16 + c;
#pragma unroll
        for (int j = 0; j < 4; j++)
          if (kg > qbase + 4 * g + j) sc[kf][j] = -1.0e30f;
      }
    }
    // ---- softmax + relay into the selected chunk state ----
    if (is_lo) sm_relay(sc, m_lo, l_lo, o_lo, ro);
    else       sm_relay(sc, m_hi, l_hi, o_hi, ro);
    // ---- tr-read P back as PV A-fragments ----
    asm volatile("s_waitcnt lgkmcnt(0)" ::: "memory");
    bf16x8 pa[2];
#pragma unroll
    for (int kc2 = 0; kc2 < 2; kc2++) {
      const unsigned base = lbase + ro + 128u * (8 * kc2 + 2 * g) + 8 * c;
      u32x2 r0 = tr_read(base);
      u32x2 r1 = tr_read(base + 128);
      pa[kc2] = combine4(r0, r1);
    }
    asm volatile("s_waitcnt lgkmcnt(0)" ::: "memory");
    __builtin_amdgcn_sched_barrier(0);
    // ---- O += P @ V ----
    if (is_lo) {
#pragma unroll
      for (int df = 0; df < 4; df++) {
        o_lo[df] = mfma16(pa[0], vb[df][0], o_lo[df]);
        o_lo[df] = mfma16(pa[1], vb[df][1], o_lo[df]);
      }
    } else {
#pragma unroll
      for (int df = 0; df < 4; df++) {
        o_hi[df] = mfma16(pa[0], vb[df][0], o_hi[df]);
        o_hi[df] = mfma16(pa[1], vb[df][1], o_hi[df]);
      }
    }
  }

  const int b = bh >> 4, h = bh & 15;
  if (w) {
    // wave 1: publish hi partial
#pragma unroll
    for (int df = 0; df < 4; df++)
#pragma unroll
      for (int j = 0; j < 4; j++)
        Om[4 * g + j][df * 16 + c] = o_hi[df][j];
    if (c == 0) {
#pragma unroll
      for (int j = 0; j < 4; j++) {
        Ml2[0][4 * g + j] = m_hi[j];
        Ml2[1][4 * g + j] = l_hi[j];
      }
    }
  } else {
    // wave 0: store completed lo chunk
    float inv[4];
#pragma unroll
    for (int j = 0; j < 4; j++) inv[j] = 1.0f / l_lo[j];
#pragma unroll
    for (int df = 0; df < 4; df++)
#pragma unroll
      for (int j = 0; j < 4; j++) {
        const int row = b * SS + ql + 4 * g + j;
        const int col = h * HD + df * 16 + c;
        AO[(size_t)row * DM + col] = (bf16)(o_lo[df][j] * inv[j]);
      }
  }
  __syncthreads();
  if (!w) {
    // wave 0: merge hi partials and store
    float a0[4], a1[4], linv[4];
#pragma unroll
    for (int j = 0; j < 4; j++) {
      const float m1 = Ml2[0][4 * g + j];
      const float l1 = Ml2[1][4 * g + j];
      const float mm = fmaxf(m_hi[j], m1);
      a0[j] = __builtin_exp2f((m_hi[j] - mm) * LOG2E);
      a1[j] = __builtin_exp2f((m1 - mm) * LOG2E);
      linv[j] = 1.0f / (a0[j] * l_hi[j] + a1[j] * l1);
    }
#pragma unroll
    for (int df = 0; df < 4; df++)
#pragma unroll
      for (int j = 0; j < 4; j++) {
        const float val = a0[j] * o_hi[df][j] + a1[j] * Om[4 * g + j][df * 16 + c];
        const int row = b * SS + qh + 4 * g + j;
        const int col = h * HD + df * 16 + c;
        AO[(size_t)row * DM + col] = (bf16)(val * linv[j]);
      }
  }
}

// ---------------- output projection -> fp32 d_out ----------------
__global__ __launch_bounds__(256, 2) void oproj_kernel(const bf16* __restrict__ AO,
    const bf16* __restrict__ wob, float* __restrict__ out) {
  f32x4 acc[4][4];
  const int rowA0 = blockIdx.y * 128, rowB0 = blockIdx.x * 128;
  gemm_bt_128(AO, wob, rowA0, rowB0, acc);
  const int t = threadIdx.x, w = t >> 6, lane = t & 63;
  const int wr = w >> 1, wc = w & 1, g = lane >> 4, c = lane & 15;
#pragma unroll
  for (int mi = 0; mi < 4; mi++)
#pragma unroll
    for (int ni = 0; ni < 4; ni++) {
      const int ncol = rowB0 + wc * 64 + ni * 16 + c;
#pragma unroll
      for (int j = 0; j < 4; j++) {
        const int mrow = rowA0 + wr * 64 + mi * 16 + 4 * g + j;
        out[(size_t)mrow * DM + ncol] = acc[mi][ni][j];
      }
    }
}

extern "C" void kernel_launch(void* const* d_in, const int* in_sizes, int n_in,
                              void* d_out, int out_size, void* d_ws, size_t ws_size,
                              hipStream_t stream) {
  const float* x  = (const float*)d_in[0];
  const float* wq = (const float*)d_in[1];
  const float* wk = (const float*)d_in[2];
  const float* wv = (const float*)d_in[3];
  const float* wo = (const float*)d_in[4];
  const int*   pos = (const int*)d_in[5];
  char* ws = (char*)d_ws;
  bf16* xb   = (bf16*)(ws + OFF_XB);
  bf16* wqkv = (bf16*)(ws + OFF_WQKV);
  bf16* wob  = (bf16*)(ws + OFF_WO);
  fx2*  tab  = (fx2*)(ws + OFF_TAB);
  bf16* Qb   = (bf16*)(ws + OFF_Q);
  bf16* Kb   = (bf16*)(ws + OFF_K);
  bf16* VTb  = (bf16*)(ws + OFF_VT);
  bf16* AOb  = (bf16*)(ws + OFF_AO);

  hipLaunchKernelGGL(prep_kernel, dim3(2048), dim3(256), 0, stream,
                     x, wq, wk, wv, wo, pos, xb, wqkv, wob, tab);
  hipLaunchKernelGGL(qkv_kernel, dim3(24, 32), dim3(256), 0, stream,
                     xb, wqkv, tab, Qb, Kb, VTb);
  hipLaunchKernelGGL(attn_kernel, dim3(64, 32), dim3(128), 0, stream,
                     Qb, Kb, VTb, AOb);
  hipLaunchKernelGGL(oproj_kernel, dim3(8, 32), dim3(256), 0, stream,
                     AOb, wob, (float*)d_out);
}